// Round 1
// baseline (272.281 us; speedup 1.0000x reference)
//
#include <hip/hip_runtime.h>

// Problem constants (from reference): S=4096, H=3, E=512, G=3334, F=1
constexpr int S = 4096;
constexpr int H = 3;
constexpr int E = 512;
constexpr int G = 3334;
constexpr float RES = 0.03f;             // INTEGRAL_RESOLUTION
constexpr float LOG2E = 1.44269504088896340736f;

constexpr int BT   = 256;                // threads per block
constexpr int NBLK = 3334;               // 3334*256*12 == S*H*G/4 exactly
constexpr int NF4G = S * H * G / 4;      // 10,242,048 float4s of grid
constexpr int GQ   = NF4G / (NBLK * BT); // 12 grid quads per thread, exact
constexpr int NF4E = S * H * E / 4;      // 1,572,864 float4s of events
constexpr int EBLK = 3072;               // blocks that also do events
constexpr int EQ   = NF4E / (EBLK * BT); // 2 event quads per thread, exact

static_assert(NBLK * BT * GQ == NF4G, "grid partition exact");
static_assert(EBLK * BT * EQ == NF4E, "event partition exact");

#if __has_builtin(__builtin_amdgcn_exp2f)
#define EXP2(x) __builtin_amdgcn_exp2f(x)
#else
#define EXP2(x) exp2f(x)
#endif

// Sum of exp2 over one float4 at float4-index fidx (flat in [S*H*G]).
// One magic-div chain per quad; in-quad row crossing handled by compare.
// Constants are pre-scaled by log2(e): exp(b + w*y) == exp2(c + v*y).
__device__ __forceinline__ float quad_exp(int fidx, float4 y,
                                          float c0, float c1, float c2,
                                          float v0, float v1, float v2) {
    int j = fidx * 4;                    // flat element index
    int q = j / G;                       // row (compiler magic-mul)
    int r = j - q * G;                   // col of elem 0
    int m = q - (q / 3) * 3;             // head of elem 0
    int hB = (m == 2) ? 0 : (m + 1);     // head after a row crossing
    float cA = (m == 0) ? c0 : ((m == 1) ? c1 : c2);
    float vA = (m == 0) ? v0 : ((m == 1) ? v1 : v2);
    float cB = (hB == 0) ? c0 : ((hB == 1) ? c1 : c2);
    float vB = (hB == 0) ? v0 : ((hB == 1) ? v1 : v2);
    int lim = G - r;                     // elems c >= lim belong to row q+1
    float s;
    s  = EXP2(cA + vA * y.x);
    s += EXP2(((1 >= lim) ? cB : cA) + ((1 >= lim) ? vB : vA) * y.y);
    s += EXP2(((2 >= lim) ? cB : cA) + ((2 >= lim) ? vB : vA) * y.z);
    s += EXP2(((3 >= lim) ? cB : cA) + ((3 >= lim) ? vB : vA) * y.w);
    return s;
}

__global__ __launch_bounds__(256) void logic_model_kernel(
    const float* __restrict__ ev,     // [S*H*E] event_features
    const int*   __restrict__ mask,   // [S*H*E] event_mask (0/1)
    const float* __restrict__ gr,     // [S*H*G] grid_features
    const float* __restrict__ w,      // [H] weights
    const float* __restrict__ bases,  // [H]
    const float* __restrict__ eff,    // [H] effects
    float* __restrict__ out)
{
    // Unscaled for Part 1 (log-sum), log2e-scaled for Part 2 (exp2).
    const float b0 = bases[0], b1 = bases[1], b2 = bases[2];
    const float w0 = w[0] * eff[0], w1 = w[1] * eff[1], w2 = w[2] * eff[2];
    const float c0 = b0 * LOG2E, c1 = b1 * LOG2E, c2 = b2 * LOG2E;
    const float v0 = w0 * LOG2E, v1 = w1 * LOG2E, v2 = w2 * LOG2E;

    const int t = threadIdx.x;
    const int b = blockIdx.x;
    const float4* ev4 = (const float4*)ev;
    const int4*   m4  = (const int4*)mask;
    const float4* gr4 = (const float4*)gr;

    // ---- Issue Part-1 (event) loads first; they retire under grid stream --
    const bool do_ev = (b < EBLK);
    const int ebase = b * (EQ * BT) + t;      // block-contiguous event chunk
    float4 ex0 = {0,0,0,0}, ex1 = {0,0,0,0};
    int4   em0 = {0,0,0,0}, em1 = {0,0,0,0};
    if (do_ev) {                              // block-uniform branch
        ex0 = ev4[ebase];      em0 = m4[ebase];
        ex1 = ev4[ebase + BT]; em1 = m4[ebase + BT];
    }
    __builtin_amdgcn_sched_barrier(0);        // keep these issued up front

    // ---- Part 2: 12 quads/thread, exact partition, no tail predication ----
    // Let the compiler pipeline the fully-unrolled load/consume sequence.
    float acc_gr = 0.f;
    const int gbase = b * (GQ * BT) + t;      // block-contiguous grid chunk
    #pragma unroll
    for (int u = 0; u < GQ; ++u) {
        int fidx = gbase + u * BT;
        acc_gr += quad_exp(fidx, gr4[fidx], c0, c1, c2, v0, v1, v2);
    }

    // ---- Part 1 compute (its loads completed long ago) --------------------
    float acc_ev = 0.f;
    if (do_ev) {
        #pragma unroll
        for (int u = 0; u < EQ; ++u) {
            int fidx = ebase + u * BT;
            int row = fidx >> 7;              // 128 float4 per (s,h) event row
            int h = row - (row / 3) * 3;
            float bb = (h == 0) ? b0 : ((h == 1) ? b1 : b2);
            float ww = (h == 0) ? w0 : ((h == 1) ? w1 : w2);
            float4 x = (u == 0) ? ex0 : ex1;
            int4   m = (u == 0) ? em0 : em1;
            if (m.x) acc_ev += bb + ww * x.x;
            if (m.y) acc_ev += bb + ww * x.y;
            if (m.z) acc_ev += bb + ww * x.z;
            if (m.w) acc_ev += bb + ww * x.w;
        }
    }

    float v = acc_ev - RES * acc_gr;

    // ---- Block reduction: wave64 shuffle -> LDS -> one atomic per block ---
    #pragma unroll
    for (int off = 32; off > 0; off >>= 1)
        v += __shfl_down(v, off, 64);

    __shared__ float sdata[4];
    const int wave = t >> 6;
    const int lane = t & 63;
    if (lane == 0) sdata[wave] = v;
    __syncthreads();
    if (t == 0) {
        float s = sdata[0] + sdata[1] + sdata[2] + sdata[3];
        atomicAdd(out, s);
    }
}

extern "C" void kernel_launch(void* const* d_in, const int* in_sizes, int n_in,
                              void* d_out, int out_size, void* d_ws, size_t ws_size,
                              hipStream_t stream) {
    const float* ev    = (const float*)d_in[0];  // event_features [S,H,E,1]
    const int*   mask  = (const int*)  d_in[1];  // event_mask     [S,H,E]
    const float* gr    = (const float*)d_in[2];  // grid_features  [S,H,G,1]
    const float* wgt   = (const float*)d_in[3];  // weights        [H,1]
    const float* bases = (const float*)d_in[4];  // bases          [H]
    const float* eff   = (const float*)d_in[5];  // effects        [H,1]
    float* out = (float*)d_out;

    // d_out is poisoned 0xAA before every timed launch — zero it (capture-legal).
    hipMemsetAsync(out, 0, sizeof(float), stream);

    logic_model_kernel<<<NBLK, BT, 0, stream>>>(ev, mask, gr, wgt, bases, eff, out);
}